// Round 6
// baseline (851.465 us; speedup 1.0000x reference)
//
#include <hip/hip_runtime.h>
#include <hip/hip_bf16.h>
#include <math.h>

#define DIM 896
#define DD  (DIM * DIM)
#define NH 8
#define HD 112
#define BB 64
#define TT 8
#define KA 65
#define KAPAD 4224   // 64*65 = 4160 padded to 33*128
#define KT 512
#define NCH 4                  // attention key chunks
#define PSTRIDE 912            // per (bh,chunk) partial: 896 O + 8 m + 8 l (floats)

#define EPI_NONE  0
#define EPI_ROPE  1
#define EPI_RESID 2
#define EPI_RELU  3

// -log2(10000)/56
#define NEG_L2_10K_OVER_56 (-0.2373327285062406f)

#ifndef __has_builtin
#define __has_builtin(x) 0
#endif
#if __has_builtin(__builtin_amdgcn_global_load_lds)
#define HAS_GLL 1
#else
#define HAS_GLL 0
#endif

typedef __attribute__((ext_vector_type(8))) short bf16x8_t;
typedef __attribute__((ext_vector_type(4))) float f32x4_t;

__device__ __forceinline__ short f2bf(float f) {  // RNE
  unsigned u = __float_as_uint(f);
  u += 0x7fffu + ((u >> 16) & 1u);
  return (short)(u >> 16);
}
__device__ __forceinline__ float bf2f(short s) {
  return __uint_as_float(((unsigned)(unsigned short)s) << 16);
}
__device__ __forceinline__ unsigned pack_bf2(unsigned u0, unsigned u1) {
  return __builtin_amdgcn_perm(u1, u0, 0x07060302u);  // hi16(u1):hi16(u0)
}

// ================= prep: 9x weight transpose + x->bf16 + h_ad build =================
// blocks [0,7056): wtrans; [7056,7280): convert x; [7280,9128): build_had
struct W9 { const float* w[9]; };

__global__ __launch_bounds__(256) void prep(
    W9 w9, short* __restrict__ WtA,
    const float* __restrict__ x, short* __restrict__ xb,
    const float* __restrict__ h_a, const float* __restrict__ p,
    short* __restrict__ hadb)
{
  __shared__ float t[32][33];
  const int bid = blockIdx.x;
  const int tid = threadIdx.x;
  if (bid < 7056) {                       // ---- wtrans: W[k][n] f32 -> Wt[n][k] bf16
    const int z = bid / 784, rem = bid % 784;
    const int bx = rem % 28, by = rem / 28;
    const float* W = w9.w[z];
    short* dst = WtA + (size_t)z * DD;
    const int tx = tid & 31, ty = tid >> 5;
#pragma unroll
    for (int i = 0; i < 4; ++i)
      t[ty + i * 8][tx] = W[(size_t)(by * 32 + ty + i * 8) * DIM + bx * 32 + tx];
    __syncthreads();
#pragma unroll
    for (int i = 0; i < 4; ++i)
      dst[(size_t)(bx * 32 + ty + i * 8) * DIM + by * 32 + tx] = f2bf(t[tx][ty + i * 8]);
  } else if (bid < 7280) {                // ---- x -> bf16 (57344 groups of 8)
    const int i = (bid - 7056) * 256 + tid;
    const float4 a = ((const float4*)x)[i * 2];
    const float4 b = ((const float4*)x)[i * 2 + 1];
    bf16x8_t o;
    o[0] = f2bf(a.x); o[1] = f2bf(a.y); o[2] = f2bf(a.z); o[3] = f2bf(a.w);
    o[4] = f2bf(b.x); o[5] = f2bf(b.y); o[6] = f2bf(b.z); o[7] = f2bf(b.w);
    ((bf16x8_t*)xb)[i] = o;
  } else {                                // ---- h_ad = concat(h_a, p) -> bf16 (zero-pad)
    const int i = (bid - 7280) * 256 + tid;     // 473088 groups of 8
    const int c = (i % 112) * 8;
    const int row = i / 112;
    bf16x8_t o;
    if (row >= BB * KA) {
#pragma unroll
      for (int j = 0; j < 8; ++j) o[j] = 0;
    } else {
      const int b = row / KA, j = row % KA;
      const float* src = (j < KA - 1) ? h_a + ((size_t)b * (KA - 1) + j) * DIM + c
                                      : p + (size_t)b * DIM + c;
      const float4 a = *(const float4*)src;
      const float4 d = *(const float4*)(src + 4);
      o[0] = f2bf(a.x); o[1] = f2bf(a.y); o[2] = f2bf(a.z); o[3] = f2bf(a.w);
      o[4] = f2bf(d.x); o[5] = f2bf(d.y); o[6] = f2bf(d.z); o[7] = f2bf(d.w);
    }
    ((bf16x8_t*)hadb)[i] = o;
  }
}

// ================= unified MFMA GEMM =================
// C[rows x nsub*896] = A[rows x 896] @ Wt + bias, per-sub epilogue.
// 128x128 tile, BK=32, 4 waves x 4x4 of 16x16x32 bf16 MFMA.
// LDS granule (16B) XOR-swizzled by row to kill bank conflicts:
//   fp32 A rows (8 granules):  pos = g ^ (row & 7)      -> 2-way (free)
//   bf16 rows  (4 granules):   pos = g ^ ((row>>1) & 3) -> 2-way (free)
struct GemmJob {
  const void* A;         // fp32 if aF else bf16, row-major [rows][896]
  const short* Wt;       // bf16 [nsub*896][896]
  const float* bias[3];
  float* outF[3];
  short* outB[3];
  const float* resid;
  int epi[3];
  int pos_mod[3];
  int nx;                // 7 * nsub
  int base;              // first linear block id
  int aF;                // A is fp32
};

__device__ __forceinline__ void gemm_body(const GemmJob& J, int bid,
                                          float* AsF, short* Bs)
{
  short* As = (short*)AsF;   // bf16-A alias (uses first 8KB)
  const int tid = threadIdx.x;
  const int wave = tid >> 6, lane = tid & 63;
  const int local = bid - J.base;
  const int bx = local % J.nx, by = local / J.nx;
  const int sub = bx / 7, col0 = (bx % 7) * 128, row0 = by * 128;
  const int wm = wave >> 1, wn = wave & 1;
  const int lm = lane & 15, lq = lane >> 4;

  // bf16 staging coords: row r4 = lane>>2, granule g4 = lane&3
  const int r4 = lane >> 2, g4 = lane & 3, sw4 = (r4 >> 1) & 3;
  const short* Wg0 = J.Wt + (size_t)(sub * DIM + col0 + wave * 32 + r4) * DIM
                     + (g4 ^ sw4) * 8;
  const short* Wg1 = Wg0 + (size_t)16 * DIM;

  f32x4_t acc[4][4];
#pragma unroll
  for (int i = 0; i < 4; ++i)
#pragma unroll
    for (int j = 0; j < 4; ++j) acc[i][j] = (f32x4_t){0.f, 0.f, 0.f, 0.f};

  if (J.aF) {
    // ---------------- fp32-A path ----------------
    const float* Af = (const float*)J.A;
    const int r8 = lane >> 3, g8 = lane & 7;
    const float* Ag = Af + (size_t)(row0 + wave * 32 + r8) * DIM + ((g8 ^ r8) * 4);

    for (int k0 = 0; k0 < DIM; k0 += 32) {
      __syncthreads();
#if HAS_GLL
#pragma unroll
      for (int i = 0; i < 4; ++i)
        __builtin_amdgcn_global_load_lds(
            (const __attribute__((address_space(1))) unsigned*)(Ag + (size_t)(i * 8) * DIM + k0),
            (__attribute__((address_space(3))) unsigned*)&AsF[(wave * 32 + i * 8) * 32], 16, 0, 0);
      __builtin_amdgcn_global_load_lds(
          (const __attribute__((address_space(1))) unsigned*)(Wg0 + k0),
          (__attribute__((address_space(3))) unsigned*)&Bs[(wave * 32) * 32], 16, 0, 0);
      __builtin_amdgcn_global_load_lds(
          (const __attribute__((address_space(1))) unsigned*)(Wg1 + k0),
          (__attribute__((address_space(3))) unsigned*)&Bs[(wave * 32 + 16) * 32], 16, 0, 0);
#else
      {
        const int m = tid >> 1, hh = tid & 1, s8 = m & 7, s4 = (m >> 1) & 3;
#pragma unroll
        for (int c = 4 * hh; c < 4 * hh + 4; ++c)
          *(float4*)&AsF[m * 32 + (c ^ s8) * 4] =
              *(const float4*)(Af + (size_t)(row0 + m) * DIM + k0 + c * 4);
#pragma unroll
        for (int c = 2 * hh; c < 2 * hh + 2; ++c)
          *(bf16x8_t*)&Bs[m * 32 + (c ^ s4) * 8] =
              *(const bf16x8_t*)(J.Wt + (size_t)(sub * DIM + col0 + m) * DIM + k0 + c * 8);
      }
#endif
      __syncthreads();

      bf16x8_t af[4], bfr[4];
#pragma unroll
      for (int t = 0; t < 4; ++t) {
        const int m = wm * 64 + t * 16 + lm;
        const int sw = m & 7;
        const float4 f0 = *(const float4*)&AsF[m * 32 + ((2 * lq) ^ sw) * 4];
        const float4 f1 = *(const float4*)&AsF[m * 32 + ((2 * lq + 1) ^ sw) * 4];
        unsigned p0 = pack_bf2(__float_as_uint(f0.x) + 0x8000u, __float_as_uint(f0.y) + 0x8000u);
        unsigned p1 = pack_bf2(__float_as_uint(f0.z) + 0x8000u, __float_as_uint(f0.w) + 0x8000u);
        unsigned p2 = pack_bf2(__float_as_uint(f1.x) + 0x8000u, __float_as_uint(f1.y) + 0x8000u);
        unsigned p3 = pack_bf2(__float_as_uint(f1.z) + 0x8000u, __float_as_uint(f1.w) + 0x8000u);
        af[t][0] = (short)(p0 & 0xffff); af[t][1] = (short)(p0 >> 16);
        af[t][2] = (short)(p1 & 0xffff); af[t][3] = (short)(p1 >> 16);
        af[t][4] = (short)(p2 & 0xffff); af[t][5] = (short)(p2 >> 16);
        af[t][6] = (short)(p3 & 0xffff); af[t][7] = (short)(p3 >> 16);
      }
#pragma unroll
      for (int t = 0; t < 4; ++t) {
        const int n = wn * 64 + t * 16 + lm;
        bfr[t] = *(const bf16x8_t*)&Bs[n * 32 + (lq ^ ((n >> 1) & 3)) * 8];
      }
#pragma unroll
      for (int tm = 0; tm < 4; ++tm)
#pragma unroll
        for (int tn = 0; tn < 4; ++tn)
          acc[tm][tn] = __builtin_amdgcn_mfma_f32_16x16x32_bf16(
              af[tm], bfr[tn], acc[tm][tn], 0, 0, 0);
    }
  } else {
    // ---------------- bf16-A path ----------------
    const short* Ab = (const short*)J.A;
    const short* Ag0 = Ab + (size_t)(row0 + wave * 32 + r4) * DIM + (g4 ^ sw4) * 8;
    const short* Ag1 = Ag0 + (size_t)16 * DIM;

    for (int k0 = 0; k0 < DIM; k0 += 32) {
      __syncthreads();
#if HAS_GLL
      __builtin_amdgcn_global_load_lds(
          (const __attribute__((address_space(1))) unsigned*)(Ag0 + k0),
          (__attribute__((address_space(3))) unsigned*)&As[(wave * 32) * 32], 16, 0, 0);
      __builtin_amdgcn_global_load_lds(
          (const __attribute__((address_space(1))) unsigned*)(Ag1 + k0),
          (__attribute__((address_space(3))) unsigned*)&As[(wave * 32 + 16) * 32], 16, 0, 0);
      __builtin_amdgcn_global_load_lds(
          (const __attribute__((address_space(1))) unsigned*)(Wg0 + k0),
          (__attribute__((address_space(3))) unsigned*)&Bs[(wave * 32) * 32], 16, 0, 0);
      __builtin_amdgcn_global_load_lds(
          (const __attribute__((address_space(1))) unsigned*)(Wg1 + k0),
          (__attribute__((address_space(3))) unsigned*)&Bs[(wave * 32 + 16) * 32], 16, 0, 0);
#else
      {
        const int m = tid >> 1, hh = tid & 1, s4 = (m >> 1) & 3;
#pragma unroll
        for (int c = 2 * hh; c < 2 * hh + 2; ++c) {
          *(bf16x8_t*)&As[m * 32 + (c ^ s4) * 8] =
              *(const bf16x8_t*)(Ab + (size_t)(row0 + m) * DIM + k0 + c * 8);
          *(bf16x8_t*)&Bs[m * 32 + (c ^ s4) * 8] =
              *(const bf16x8_t*)(J.Wt + (size_t)(sub * DIM + col0 + m) * DIM + k0 + c * 8);
        }
      }
#endif
      __syncthreads();

      bf16x8_t af[4], bfr[4];
#pragma unroll
      for (int t = 0; t < 4; ++t) {
        const int m = wm * 64 + t * 16 + lm;
        af[t] = *(const bf16x8_t*)&As[m * 32 + (lq ^ ((m >> 1) & 3)) * 8];
      }
#pragma unroll
      for (int t = 0; t < 4; ++t) {
        const int n = wn * 64 + t * 16 + lm;
        bfr[t] = *(const bf16x8_t*)&Bs[n * 32 + (lq ^ ((n >> 1) & 3)) * 8];
      }
#pragma unroll
      for (int tm = 0; tm < 4; ++tm)
#pragma unroll
        for (int tn = 0; tn < 4; ++tn)
          acc[tm][tn] = __builtin_amdgcn_mfma_f32_16x16x32_bf16(
              af[tm], bfr[tn], acc[tm][tn], 0, 0, 0);
    }
  }

  // ---------------- epilogue — C/D frag: row = lq*4 + reg, col = lm ----------------
  const float* bias = J.bias[sub];
  float* outF = J.outF[sub];
  short* outB = J.outB[sub];
  const int epi = J.epi[sub], pm = J.pos_mod[sub];
#pragma unroll
  for (int tn = 0; tn < 4; ++tn) {
    const int col = col0 + wn * 64 + tn * 16 + lm;
    const float bv = bias[col];
    float fr = 0.f, sgn = 0.f;
    if (epi == EPI_ROPE) {
      const int d0 = col % HD;
      fr = exp2f((float)(d0 % 56) * NEG_L2_10K_OVER_56);
      sgn = (d0 & 1) ? 1.f : -1.f;
    }
#pragma unroll
    for (int tm = 0; tm < 4; ++tm) {
#pragma unroll
      for (int r = 0; r < 4; ++r) {
        const int grow = row0 + wm * 64 + tm * 16 + lq * 4 + r;
        float v = acc[tm][tn][r] + bv;
        if (epi == EPI_ROPE) {
          const float prt = __shfl_xor(v, 1);
          float s, c;
          __sincosf((float)(grow % pm) * fr, &s, &c);
          v = v * c + sgn * prt * s;
        } else if (epi == EPI_RESID) {
          v += J.resid[(size_t)grow * DIM + col];
        } else if (epi == EPI_RELU) {
          v = fmaxf(v, 0.f);
        }
        if (outB) outB[(size_t)grow * DIM + col] = f2bf(v);
        else      outF[(size_t)grow * DIM + col] = v;
      }
    }
  }
}

__global__ __launch_bounds__(256) void gemm_multi(GemmJob J0, GemmJob J1, GemmJob J2)
{
  __shared__ __align__(16) float AsF[128 * 32];   // 16 KB (bf16 path uses first 8 KB)
  __shared__ __align__(16) short Bs[128 * 32];    // 8 KB
  const int bid = blockIdx.x;
  GemmJob J = (bid >= J2.base) ? J2 : ((bid >= J1.base) ? J1 : J0);
  gemm_body(J, bid, AsF, Bs);
}

__global__ __launch_bounds__(256) void gemm_single(GemmJob J)
{
  __shared__ __align__(16) float AsF[128 * 32];
  __shared__ __align__(16) short Bs[128 * 32];
  gemm_body(J, blockIdx.x, AsF, Bs);
}

// ================= attention, split-K partials =================
// grid (512, NCH). chunk 0: 73 self+ad keys; chunks 1..3: 171/171/170 task keys.
__global__ __launch_bounds__(256) void attn_part(
    const short* __restrict__ q, const short* __restrict__ k_s,
    const short* __restrict__ k_a, const short* __restrict__ k_t,
    const short* __restrict__ v_s, const short* __restrict__ v_a,
    const short* __restrict__ v_t, const float* __restrict__ gate,
    float* __restrict__ part)
{
  __shared__ float qs[HD][TT];
  __shared__ float sc[TT][176];
  __shared__ float msh[TT], lsh[TT];
  const int tid = threadIdx.x;
  const int bh = blockIdx.x, b = bh >> 3, h = bh & 7;
  const int ch = blockIdx.y;
  const float scale = 0.09449111825230681f;  // 1/sqrt(112)
  const int nk = (ch == 0) ? (TT + KA) : ((ch == 3) ? 170 : 171);
  const int t0 = (ch >= 1) ? (ch - 1) * 171 : 0;

  for (int idx = tid; idx < TT * HD; idx += 256) {
    const int t = idx / HD, d = idx % HD;
    qs[d][t] = bf2f(q[(size_t)(b * TT + t) * DIM + h * HD + d]);
  }
  __syncthreads();

  if (tid < nk) {
    const short* kp;
    float s = scale;
    if (ch == 0) {
      kp = (tid < TT) ? k_s + (size_t)(b * TT + tid) * DIM + h * HD
                      : k_a + (size_t)(b * KA + (tid - TT)) * DIM + h * HD;
    } else {
      kp = k_t + (size_t)(b * KT + t0 + tid) * DIM + h * HD;
      s = scale * tanhf(gate[0]);
    }
    float dot[TT] = {};
    for (int d8 = 0; d8 < HD; d8 += 8) {
      const bf16x8_t kv8 = *(const bf16x8_t*)(kp + d8);
#pragma unroll
      for (int j = 0; j < 8; ++j) {
        const float kv = bf2f(kv8[j]);
#pragma unroll
        for (int t = 0; t < TT; ++t) dot[t] = fmaf(qs[d8 + j][t], kv, dot[t]);
      }
    }
#pragma unroll
    for (int t = 0; t < TT; ++t) sc[t][tid] = dot[t] * s;
  }
  __syncthreads();

  const int wave = tid >> 6, lane = tid & 63;
  for (int t = wave; t < TT; t += 4) {
    float m = -1e30f;
    for (int k = lane; k < nk; k += 64) m = fmaxf(m, sc[t][k]);
#pragma unroll
    for (int o = 32; o >= 1; o >>= 1) m = fmaxf(m, __shfl_xor(m, o));
    float sum = 0.f;
    for (int k = lane; k < nk; k += 64) {
      const float e = expf(sc[t][k] - m);
      sc[t][k] = e;
      sum += e;
    }
#pragma unroll
    for (int o = 32; o >= 1; o >>= 1) sum += __shfl_xor(sum, o);
    if (lane == 0) { msh[t] = m; lsh[t] = sum; }
  }
  __syncthreads();

  float* pb = part + (size_t)(bh * NCH + ch) * PSTRIDE;
  for (int idx = tid; idx < TT * HD; idx += 256) {
    const int t = idx / HD, d = idx % HD;
    float acc = 0.f;
    if (ch == 0) {
      const short* vs = v_s + (size_t)(b * TT) * DIM + h * HD + d;
#pragma unroll
      for (int k = 0; k < TT; ++k)
        acc = fmaf(sc[t][k], bf2f(vs[(size_t)k * DIM]), acc);
      const short* va = v_a + (size_t)(b * KA) * DIM + h * HD + d;
      for (int k = 0; k < KA; ++k)
        acc = fmaf(sc[t][TT + k], bf2f(va[(size_t)k * DIM]), acc);
    } else {
      const short* vt = v_t + (size_t)(b * KT + t0) * DIM + h * HD + d;
      for (int k = 0; k < nk; ++k)
        acc = fmaf(sc[t][k], bf2f(vt[(size_t)k * DIM]), acc);
    }
    pb[t * HD + d] = acc;
  }
  if (tid < TT) {
    pb[TT * HD + tid] = msh[tid];
    pb[TT * HD + TT + tid] = lsh[tid];
  }
}

__global__ __launch_bounds__(256) void attn_reduce(
    const float* __restrict__ part, short* __restrict__ out)
{
  __shared__ float fac[NCH][TT], inv[TT];
  const int tid = threadIdx.x;
  const int bh = blockIdx.x, b = bh >> 3, h = bh & 7;
  const float* pb = part + (size_t)bh * NCH * PSTRIDE;
  if (tid < TT) {
    const int t = tid;
    float M = -1e30f;
#pragma unroll
    for (int c = 0; c < NCH; ++c) M = fmaxf(M, pb[c * PSTRIDE + TT * HD + t]);
    float S = 0.f;
#pragma unroll
    for (int c = 0; c < NCH; ++c) {
      const float f = expf(pb[c * PSTRIDE + TT * HD + t] - M);
      fac[c][t] = f;
      S += pb[c * PSTRIDE + TT * HD + TT + t] * f;
    }
    inv[t] = 1.f / S;
  }
  __syncthreads();
  for (int idx = tid; idx < TT * HD; idx += 256) {
    const int t = idx / HD, d = idx % HD;
    float o = 0.f;
#pragma unroll
    for (int c = 0; c < NCH; ++c) o = fmaf(pb[c * PSTRIDE + t * HD + d], fac[c][t], o);
    out[(size_t)(b * TT + t) * DIM + h * HD + d] = f2bf(o * inv[t]);
  }
}

// ================= layernorm: fp32 in -> bf16 out =================
__global__ __launch_bounds__(256) void ln_kernel(
    const float* __restrict__ y, const float* __restrict__ g,
    const float* __restrict__ beta, short* __restrict__ yn)
{
  __shared__ float s1[4], s2[4];
  const int r = blockIdx.x, tid = threadIdx.x;
  const float* row = y + (size_t)r * DIM;
  float sum = 0.f, sq = 0.f;
  for (int c = tid; c < DIM; c += 256) {
    const float v = row[c];
    sum += v;
    sq = fmaf(v, v, sq);
  }
#pragma unroll
  for (int o = 32; o >= 1; o >>= 1) {
    sum += __shfl_xor(sum, o);
    sq  += __shfl_xor(sq, o);
  }
  const int wave = tid >> 6, lane = tid & 63;
  if (lane == 0) { s1[wave] = sum; s2[wave] = sq; }
  __syncthreads();
  sum = s1[0] + s1[1] + s1[2] + s1[3];
  sq  = s2[0] + s2[1] + s2[2] + s2[3];
  const float mu = sum / DIM;
  const float var = sq / DIM - mu * mu;
  const float rstd = 1.f / sqrtf(var + 1e-5f);
  for (int c = tid; c < DIM; c += 256)
    yn[(size_t)r * DIM + c] = f2bf((row[c] - mu) * rstd * g[c] + beta[c]);
}

// ================= launch =================
extern "C" void kernel_launch(void* const* d_in, const int* in_sizes, int n_in,
                              void* d_out, int out_size, void* d_ws, size_t ws_size,
                              hipStream_t stream)
{
  const float* x   = (const float*)d_in[0];
  const float* h_a = (const float*)d_in[1];
  const float* h_t = (const float*)d_in[2];
  const float* p   = (const float*)d_in[3];
  const float* Wq  = (const float*)d_in[4];  const float* bq  = (const float*)d_in[5];
  const float* Wks = (const float*)d_in[6];  const float* bks = (const float*)d_in[7];
  const float* Wvs = (const float*)d_in[8];  const float* bvs = (const float*)d_in[9];
  const float* Wka = (const float*)d_in[10]; const float* bka = (const float*)d_in[11];
  const float* Wva = (const float*)d_in[12]; const float* bva = (const float*)d_in[13];
  const float* Wkt = (const float*)d_in[14]; const float* bkt = (const float*)d_in[15];
  const float* Wvt = (const float*)d_in[16]; const float* bvt = (const float*)d_in[17];
  const float* Wo  = (const float*)d_in[18]; const float* bo  = (const float*)d_in[19];
  const float* Wf  = (const float*)d_in[20]; const float* bf_ = (const float*)d_in[21];
  const float* gate = (const float*)d_in[22];
  const float* ln_g = (const float*)d_in[23];
  const float* ln_b = (const float*)d_in[24];

  // ---- workspace (bytes); total 161.9 MB < proven 167.7 MB ----
  const size_t SZ_HAD = (size_t)KAPAD * DIM * 2;
  const size_t SZ_SM  = (size_t)BB * TT * DIM * 2;
  const size_t SZ_T   = (size_t)BB * KT * DIM * 2;
  const size_t SZ_WT  = (size_t)9 * DD * 2;
  const size_t needed = SZ_HAD * 3 + SZ_SM * 6 + SZ_T * 2 + SZ_WT
                        + (size_t)BB * TT * DIM * 4;
  if (ws_size < needed) return;

  char* wsp = (char*)d_ws;
  short* hadb = (short*)wsp; wsp += SZ_HAD;
  short* xb   = (short*)wsp; wsp += SZ_SM;
  short* qb   = (short*)wsp; wsp += SZ_SM;
  short* ksb  = (short*)wsp; wsp += SZ_SM;
  short* vsb  = (short*)wsp; wsp += SZ_SM;
  short* kab  = (short*)wsp; wsp += SZ_HAD;
  short* vab  = (short*)wsp; wsp += SZ_HAD;
  short* ktb  = (short*)wsp; wsp += SZ_T;
  short* vtb  = (short*)wsp; wsp += SZ_T;
  short* WtA  = (short*)wsp; wsp += SZ_WT;
  short* attn_outb = (short*)wsp; wsp += SZ_SM;
  float* yb   = (float*)wsp; wsp += (size_t)BB * TT * DIM * 4;
  short* ynb  = (short*)wsp; wsp += SZ_SM;
  float* part = (float*)hadb;  // 7.47 MB aliases hadb (dead after A-group GEMM)

  dim3 blk(256);

  // 0) prep: weight transpose + x->bf16 + h_ad build (one dispatch)
  W9 w9; const float* Ws[9] = {Wq, Wks, Wvs, Wka, Wva, Wkt, Wvt, Wo, Wf};
  for (int i = 0; i < 9; ++i) w9.w[i] = Ws[i];
  prep<<<9128, blk, 0, stream>>>(w9, WtA, x, xb, h_a, p, hadb);

  // 1) mega-GEMM: T (fp32 A, 3584 blocks) + A-group (462) + S-group (84)
  GemmJob JT = {}, JA = {}, JS = {};
  JT.A = h_t; JT.Wt = WtA + (size_t)5 * DD; JT.nx = 14; JT.base = 0; JT.aF = 1;
  JT.bias[0] = bkt; JT.outB[0] = ktb; JT.epi[0] = EPI_ROPE; JT.pos_mod[0] = KT;
  JT.bias[1] = bvt; JT.outB[1] = vtb; JT.epi[1] = EPI_NONE; JT.pos_mod[1] = 1;
  JA.A = hadb; JA.Wt = WtA + (size_t)3 * DD; JA.nx = 14; JA.base = 3584; JA.aF = 0;
  JA.bias[0] = bka; JA.outB[0] = kab; JA.epi[0] = EPI_ROPE; JA.pos_mod[0] = KA;
  JA.bias[1] = bva; JA.outB[1] = vab; JA.epi[1] = EPI_NONE; JA.pos_mod[1] = 1;
  JS.A = xb; JS.Wt = WtA; JS.nx = 21; JS.base = 3584 + 462; JS.aF = 0;
  JS.bias[0] = bq;  JS.outB[0] = qb;  JS.epi[0] = EPI_ROPE; JS.pos_mod[0] = TT;
  JS.bias[1] = bks; JS.outB[1] = ksb; JS.epi[1] = EPI_ROPE; JS.pos_mod[1] = TT;
  JS.bias[2] = bvs; JS.outB[2] = vsb; JS.epi[2] = EPI_NONE; JS.pos_mod[2] = 1;
  gemm_multi<<<3584 + 462 + 84, blk, 0, stream>>>(JT, JA, JS);

  // 2) attention: split-K partials + combine
  attn_part<<<dim3(BB * NH, NCH), blk, 0, stream>>>(qb, ksb, kab, ktb, vsb, vab, vtb,
                                                    gate, part);
  attn_reduce<<<BB * NH, blk, 0, stream>>>(part, attn_outb);

  // 3) out-proj + residual, LN, FFN + ReLU
  {
    GemmJob J = {};
    J.A = attn_outb; J.Wt = WtA + (size_t)7 * DD; J.nx = 7; J.base = 0; J.aF = 0;
    J.bias[0] = bo; J.outF[0] = yb; J.epi[0] = EPI_RESID; J.pos_mod[0] = 1;
    J.resid = x;
    gemm_single<<<dim3(7 * 4), blk, 0, stream>>>(J);
  }
  ln_kernel<<<BB * TT, blk, 0, stream>>>(yb, ln_g, ln_b, ynb);
  {
    GemmJob J = {};
    J.A = ynb; J.Wt = WtA + (size_t)8 * DD; J.nx = 7; J.base = 0; J.aF = 0;
    J.bias[0] = bf_; J.outF[0] = (float*)d_out; J.epi[0] = EPI_RELU; J.pos_mod[0] = 1;
    gemm_single<<<dim3(7 * 4), blk, 0, stream>>>(J);
  }
}

// Round 7
// 830.508 us; speedup vs baseline: 1.0252x; 1.0252x over previous
//
#include <hip/hip_runtime.h>
#include <hip/hip_bf16.h>
#include <math.h>

#define DIM 896
#define DD  (DIM * DIM)
#define NH 8
#define HD 112
#define BB 64
#define TT 8
#define KA 65
#define KAPAD 4224   // 64*65 = 4160 padded to 33*128
#define KT 512
#define NCH 4                  // attention key chunks
#define PSTRIDE 912            // per (bh,chunk) partial: 896 O + 8 m + 8 l (floats)

#define EPI_NONE  0
#define EPI_ROPE  1
#define EPI_RESID 2
#define EPI_RELU  3

// output layouts
#define OUT_F32 0   // scattered fp32 row-major (tail GEMMs)
#define OUT_T   1   // bf16 head-major [b*8+h][512 keys][112]
#define OUT_A   2   // bf16 head-major [b*8+h][65 keys][112] (pad rows skipped)
#define OUT_S   3   // bf16 head-major [b*8+h][8 t][112]

// -log2(10000)/56
#define NEG_L2_10K_OVER_56 (-0.2373327285062406f)

#ifndef __has_builtin
#define __has_builtin(x) 0
#endif
#if __has_builtin(__builtin_amdgcn_global_load_lds)
#define HAS_GLL 1
#define GLL(gsrc, ldst) __builtin_amdgcn_global_load_lds( \
    (const __attribute__((address_space(1))) unsigned*)(gsrc), \
    (__attribute__((address_space(3))) unsigned*)(ldst), 16, 0, 0)
#else
#define HAS_GLL 0
#endif

typedef __attribute__((ext_vector_type(8))) short bf16x8_t;
typedef __attribute__((ext_vector_type(4))) float f32x4_t;

__device__ __forceinline__ short f2bf(float f) {  // RNE
  unsigned u = __float_as_uint(f);
  u += 0x7fffu + ((u >> 16) & 1u);
  return (short)(u >> 16);
}
__device__ __forceinline__ float bf2f(short s) {
  return __uint_as_float(((unsigned)(unsigned short)s) << 16);
}
__device__ __forceinline__ unsigned pack_bf2(unsigned u0, unsigned u1) {
  return __builtin_amdgcn_perm(u1, u0, 0x07060302u);  // hi16(u1):hi16(u0)
}

// ================= prep: 9x weight transpose + x->bf16 + h_ad build =================
struct W9 { const float* w[9]; };

__global__ __launch_bounds__(256) void prep(
    W9 w9, short* __restrict__ WtA,
    const float* __restrict__ x, short* __restrict__ xb,
    const float* __restrict__ h_a, const float* __restrict__ p,
    short* __restrict__ hadb)
{
  __shared__ float t[32][33];
  const int bid = blockIdx.x;
  const int tid = threadIdx.x;
  if (bid < 7056) {                       // wtrans: W[k][n] f32 -> Wt[n][k] bf16
    const int z = bid / 784, rem = bid % 784;
    const int bx = rem % 28, by = rem / 28;
    const float* W = w9.w[z];
    short* dst = WtA + (size_t)z * DD;
    const int tx = tid & 31, ty = tid >> 5;
#pragma unroll
    for (int i = 0; i < 4; ++i)
      t[ty + i * 8][tx] = W[(size_t)(by * 32 + ty + i * 8) * DIM + bx * 32 + tx];
    __syncthreads();
#pragma unroll
    for (int i = 0; i < 4; ++i)
      dst[(size_t)(bx * 32 + ty + i * 8) * DIM + by * 32 + tx] = f2bf(t[tx][ty + i * 8]);
  } else if (bid < 7280) {                // x -> bf16
    const int i = (bid - 7056) * 256 + tid;
    const float4 a = ((const float4*)x)[i * 2];
    const float4 b = ((const float4*)x)[i * 2 + 1];
    bf16x8_t o;
    o[0] = f2bf(a.x); o[1] = f2bf(a.y); o[2] = f2bf(a.z); o[3] = f2bf(a.w);
    o[4] = f2bf(b.x); o[5] = f2bf(b.y); o[6] = f2bf(b.z); o[7] = f2bf(b.w);
    ((bf16x8_t*)xb)[i] = o;
  } else {                                // h_ad = concat(h_a, p) -> bf16, zero-pad
    const int i = (bid - 7280) * 256 + tid;
    const int c = (i % 112) * 8;
    const int row = i / 112;
    bf16x8_t o;
    if (row >= BB * KA) {
#pragma unroll
      for (int j = 0; j < 8; ++j) o[j] = 0;
    } else {
      const int b = row / KA, j = row % KA;
      const float* src = (j < KA - 1) ? h_a + ((size_t)b * (KA - 1) + j) * DIM + c
                                      : p + (size_t)b * DIM + c;
      const float4 a = *(const float4*)src;
      const float4 d = *(const float4*)(src + 4);
      o[0] = f2bf(a.x); o[1] = f2bf(a.y); o[2] = f2bf(a.z); o[3] = f2bf(a.w);
      o[4] = f2bf(d.x); o[5] = f2bf(d.y); o[6] = f2bf(d.z); o[7] = f2bf(d.w);
    }
    ((bf16x8_t*)hadb)[i] = o;
  }
}

// ================= unified MFMA GEMM (dbuf + XCD swizzle + staged epilogue) ===========
struct GemmJob {
  const void* A;         // fp32 if aF else bf16, row-major [rows][896]
  const short* Wt;       // bf16 [nsub*896][896]
  const float* bias[3];
  float* outF[3];
  short* outB[3];
  const float* resid;
  int epi[3];
  int pos_mod[3];
  int okind[3];
  int nx;                // 7 * nsub
  int base;              // first linear block id
  int aF;                // A is fp32
  int xsw;               // XCD-aware swizzle (requires rowsb % 8 == 0)
  int rowsb;             // number of 128-row stripes
};

// shared: [0,32K) A dbuf (fp32: 2x16K; bf16: 2x8K in first 16K) / C-stage (32K)
//         [32K,48K) B dbuf 2x8K
__device__ __forceinline__ void gemm_body(const GemmJob& J, int bid, char* smem)
{
  const int tid = threadIdx.x;
  const int wave = tid >> 6, lane = tid & 63;
  const int local = bid - J.base;
  int bx, by;
  if (J.xsw) {
    const int xcd = local & 7, i = local >> 3;
    const int spx = J.rowsb >> 3;       // stripes per XCD
    const int si = i / J.nx;
    by = xcd * spx + si;
    bx = i - si * J.nx;
  } else {
    bx = local % J.nx; by = local / J.nx;
  }
  const int sub = bx / 7, col0 = (bx % 7) * 128, row0 = by * 128;
  const int wm = wave >> 1, wn = wave & 1;
  const int lm = lane & 15, lq = lane >> 4;

  short* Bs0 = (short*)(smem + 32768);
  short* Bs1 = (short*)(smem + 32768 + 8192);

  // B staging: lane -> row r4 = lane>>2 (+16), granule g4 = lane&3, swizzled
  const int r4 = lane >> 2, g4 = lane & 3, sw4 = (r4 >> 1) & 3;
  const short* Wg0 = J.Wt + (size_t)(sub * DIM + col0 + wave * 32 + r4) * DIM + (g4 ^ sw4) * 8;
  const short* Wg1 = Wg0 + (size_t)16 * DIM;

  f32x4_t acc[4][4];
#pragma unroll
  for (int i = 0; i < 4; ++i)
#pragma unroll
    for (int j = 0; j < 4; ++j) acc[i][j] = (f32x4_t){0.f, 0.f, 0.f, 0.f};

  if (J.aF) {
    // ---------------- fp32-A path ----------------
    float* Af0 = (float*)smem;
    float* Af1 = (float*)(smem + 16384);
    const float* Af = (const float*)J.A;
    const int r8 = lane >> 3, g8 = lane & 7;
    const float* Ag = Af + (size_t)(row0 + wave * 32 + r8) * DIM + ((g8 ^ r8) * 4);

#if HAS_GLL
    {  // preload slab 0 -> buf0
#pragma unroll
      for (int i = 0; i < 4; ++i)
        GLL(Ag + (size_t)(i * 8) * DIM, &Af0[(wave * 32 + i * 8) * 32]);
      GLL(Wg0, &Bs0[(wave * 32) * 32]);
      GLL(Wg1, &Bs0[(wave * 32 + 16) * 32]);
    }
    int cur = 0;
    for (int k0 = 0; k0 < DIM; k0 += 32) {
      __syncthreads();   // drains prefetch issued last iter (one compute-phase old)
      float* Ac = cur ? Af1 : Af0;
      short* Bc = cur ? Bs1 : Bs0;
      if (k0 + 32 < DIM) {
        float* Ad = cur ? Af0 : Af1;
        short* Bd = cur ? Bs0 : Bs1;
#pragma unroll
        for (int i = 0; i < 4; ++i)
          GLL(Ag + (size_t)(i * 8) * DIM + k0 + 32, &Ad[(wave * 32 + i * 8) * 32]);
        GLL(Wg0 + k0 + 32, &Bd[(wave * 32) * 32]);
        GLL(Wg1 + k0 + 32, &Bd[(wave * 32 + 16) * 32]);
      }
#else
    int cur = 0;
    for (int k0 = 0; k0 < DIM; k0 += 32) {
      __syncthreads();
      float* Ac = Af0;
      short* Bc = Bs0;
      {
        const int m = tid >> 1, hh = tid & 1, s8 = m & 7, s4 = (m >> 1) & 3;
#pragma unroll
        for (int c = 4 * hh; c < 4 * hh + 4; ++c)
          *(float4*)&Ac[m * 32 + (c ^ s8) * 4] =
              *(const float4*)(Af + (size_t)(row0 + m) * DIM + k0 + c * 4);
#pragma unroll
        for (int c = 2 * hh; c < 2 * hh + 2; ++c)
          *(bf16x8_t*)&Bc[m * 32 + (c ^ s4) * 8] =
              *(const bf16x8_t*)(J.Wt + (size_t)(sub * DIM + col0 + m) * DIM + k0 + c * 8);
      }
      __syncthreads();
#endif
      bf16x8_t af[4], bfr[4];
#pragma unroll
      for (int t = 0; t < 4; ++t) {
        const int m = wm * 64 + t * 16 + lm;
        const int sw = m & 7;
        const float4 f0 = *(const float4*)&Ac[m * 32 + ((2 * lq) ^ sw) * 4];
        const float4 f1 = *(const float4*)&Ac[m * 32 + ((2 * lq + 1) ^ sw) * 4];
        unsigned p0 = pack_bf2(__float_as_uint(f0.x) + 0x8000u, __float_as_uint(f0.y) + 0x8000u);
        unsigned p1 = pack_bf2(__float_as_uint(f0.z) + 0x8000u, __float_as_uint(f0.w) + 0x8000u);
        unsigned p2 = pack_bf2(__float_as_uint(f1.x) + 0x8000u, __float_as_uint(f1.y) + 0x8000u);
        unsigned p3 = pack_bf2(__float_as_uint(f1.z) + 0x8000u, __float_as_uint(f1.w) + 0x8000u);
        af[t][0] = (short)(p0 & 0xffff); af[t][1] = (short)(p0 >> 16);
        af[t][2] = (short)(p1 & 0xffff); af[t][3] = (short)(p1 >> 16);
        af[t][4] = (short)(p2 & 0xffff); af[t][5] = (short)(p2 >> 16);
        af[t][6] = (short)(p3 & 0xffff); af[t][7] = (short)(p3 >> 16);
      }
#pragma unroll
      for (int t = 0; t < 4; ++t) {
        const int n = wn * 64 + t * 16 + lm;
        bfr[t] = *(const bf16x8_t*)&Bc[n * 32 + (lq ^ ((n >> 1) & 3)) * 8];
      }
#pragma unroll
      for (int tm = 0; tm < 4; ++tm)
#pragma unroll
        for (int tn = 0; tn < 4; ++tn)
          acc[tm][tn] = __builtin_amdgcn_mfma_f32_16x16x32_bf16(
              af[tm], bfr[tn], acc[tm][tn], 0, 0, 0);
      cur ^= 1;
    }
  } else {
    // ---------------- bf16-A path ----------------
    short* Ab0 = (short*)smem;
    short* Ab1 = (short*)(smem + 8192);
    const short* Ab = (const short*)J.A;
    const short* Ag0 = Ab + (size_t)(row0 + wave * 32 + r4) * DIM + (g4 ^ sw4) * 8;
    const short* Ag1 = Ag0 + (size_t)16 * DIM;

#if HAS_GLL
    {
      GLL(Ag0, &Ab0[(wave * 32) * 32]);
      GLL(Ag1, &Ab0[(wave * 32 + 16) * 32]);
      GLL(Wg0, &Bs0[(wave * 32) * 32]);
      GLL(Wg1, &Bs0[(wave * 32 + 16) * 32]);
    }
    int cur = 0;
    for (int k0 = 0; k0 < DIM; k0 += 32) {
      __syncthreads();
      short* Ac = cur ? Ab1 : Ab0;
      short* Bc = cur ? Bs1 : Bs0;
      if (k0 + 32 < DIM) {
        short* Ad = cur ? Ab0 : Ab1;
        short* Bd = cur ? Bs0 : Bs1;
        GLL(Ag0 + k0 + 32, &Ad[(wave * 32) * 32]);
        GLL(Ag1 + k0 + 32, &Ad[(wave * 32 + 16) * 32]);
        GLL(Wg0 + k0 + 32, &Bd[(wave * 32) * 32]);
        GLL(Wg1 + k0 + 32, &Bd[(wave * 32 + 16) * 32]);
      }
#else
    int cur = 0;
    for (int k0 = 0; k0 < DIM; k0 += 32) {
      __syncthreads();
      short* Ac = Ab0;
      short* Bc = Bs0;
      {
        const int m = tid >> 1, hh = tid & 1, s4 = (m >> 1) & 3;
#pragma unroll
        for (int c = 2 * hh; c < 2 * hh + 2; ++c) {
          *(bf16x8_t*)&Ac[m * 32 + (c ^ s4) * 8] =
              *(const bf16x8_t*)(Ab + (size_t)(row0 + m) * DIM + k0 + c * 8);
          *(bf16x8_t*)&Bc[m * 32 + (c ^ s4) * 8] =
              *(const bf16x8_t*)(J.Wt + (size_t)(sub * DIM + col0 + m) * DIM + k0 + c * 8);
        }
      }
      __syncthreads();
#endif
      bf16x8_t af[4], bfr[4];
#pragma unroll
      for (int t = 0; t < 4; ++t) {
        const int m = wm * 64 + t * 16 + lm;
        af[t] = *(const bf16x8_t*)&Ac[m * 32 + (lq ^ ((m >> 1) & 3)) * 8];
      }
#pragma unroll
      for (int t = 0; t < 4; ++t) {
        const int n = wn * 64 + t * 16 + lm;
        bfr[t] = *(const bf16x8_t*)&Bc[n * 32 + (lq ^ ((n >> 1) & 3)) * 8];
      }
#pragma unroll
      for (int tm = 0; tm < 4; ++tm)
#pragma unroll
        for (int tn = 0; tn < 4; ++tn)
          acc[tm][tn] = __builtin_amdgcn_mfma_f32_16x16x32_bf16(
              af[tm], bfr[tn], acc[tm][tn], 0, 0, 0);
      cur ^= 1;
    }
  }

  // ---------------- epilogue — C/D frag: row = lq*4 + reg, col = lm ----------------
  const float* bias = J.bias[sub];
  const int epi = J.epi[sub], pm = J.pos_mod[sub], ok = J.okind[sub];

  if (ok == OUT_F32) {
    float* outF = J.outF[sub];
#pragma unroll
    for (int tn = 0; tn < 4; ++tn) {
      const int col = col0 + wn * 64 + tn * 16 + lm;
      const float bv = bias[col];
#pragma unroll
      for (int tm = 0; tm < 4; ++tm) {
#pragma unroll
        for (int r = 0; r < 4; ++r) {
          const int grow = row0 + wm * 64 + tm * 16 + lq * 4 + r;
          float v = acc[tm][tn][r] + bv;
          if (epi == EPI_RESID)      v += J.resid[(size_t)grow * DIM + col];
          else if (epi == EPI_RELU)  v = fmaxf(v, 0.f);
          outF[(size_t)grow * DIM + col] = v;
        }
      }
    }
  } else {
    short* outB = J.outB[sub];
    short* Cs = (short*)smem;       // 32 KB tile stage (overlays A/B bufs)
    __syncthreads();                // all MFMA LDS reads done before overwrite
#pragma unroll
    for (int tn = 0; tn < 4; ++tn) {
      const int lcol = wn * 64 + tn * 16 + lm;
      const int col = col0 + lcol;
      const float bv = bias[col];
      float fr = 0.f, sgn = 0.f;
      if (epi == EPI_ROPE) {
        const int d0 = col % HD;
        fr = exp2f((float)(d0 % 56) * NEG_L2_10K_OVER_56);
        sgn = (d0 & 1) ? 1.f : -1.f;
      }
#pragma unroll
      for (int tm = 0; tm < 4; ++tm) {
#pragma unroll
        for (int r = 0; r < 4; ++r) {
          const int lrow = wm * 64 + tm * 16 + lq * 4 + r;
          float v = acc[tm][tn][r] + bv;
          if (epi == EPI_ROPE) {
            const float prt = __shfl_xor(v, 1);
            float s, c;
            __sincosf((float)((row0 + lrow) % pm) * fr, &s, &c);
            v = v * c + sgn * prt * s;
          }
          Cs[lrow * 128 + lcol] = f2bf(v);
        }
      }
    }
    __syncthreads();
    // coalesced head-major write-out: 16 granules x 16 rows per round, 8 rounds
    const int g = tid & 15, rs = tid >> 4;
    const int col = col0 + g * 8;
    const int h = col / HD, d0 = col - h * HD;
#pragma unroll
    for (int rnd = 0; rnd < 8; ++rnd) {
      const int lrow = rnd * 16 + rs;
      const int grow = row0 + lrow;
      const bf16x8_t val = *(const bf16x8_t*)&Cs[lrow * 128 + g * 8];
      size_t dst;
      if (ok == OUT_T) {
        dst = (((size_t)((grow >> 9) * NH + h)) * KT + (grow & 511)) * HD + d0;
      } else if (ok == OUT_S) {
        dst = (((size_t)((grow >> 3) * NH + h)) * TT + (grow & 7)) * HD + d0;
      } else {  // OUT_A
        if (grow >= BB * KA) continue;
        const int b = grow / 65, j = grow - b * 65;
        dst = (((size_t)(b * NH + h)) * KA + j) * HD + d0;
      }
      *(bf16x8_t*)&outB[dst] = val;
    }
  }
}

__global__ __launch_bounds__(256) void gemm_multi(GemmJob J0, GemmJob J1, GemmJob J2)
{
  __shared__ __align__(16) char smem[49152];
  const int bid = blockIdx.x;
  const GemmJob& J = (bid >= J2.base) ? J2 : ((bid >= J1.base) ? J1 : J0);
  gemm_body(J, bid, smem);
}

__global__ __launch_bounds__(256) void gemm_single(GemmJob J)
{
  __shared__ __align__(16) char smem[49152];
  gemm_body(J, blockIdx.x, smem);
}

// ================= attention, split-K partials (head-major KV) =================
// grid (512, NCH). chunk 0: 8 self + 65 ad; chunks 1..3: 171/171/170 task keys.
__global__ __launch_bounds__(256) void attn_part(
    const short* __restrict__ qh, const short* __restrict__ ksh,
    const short* __restrict__ kah, const short* __restrict__ kth,
    const short* __restrict__ vsh, const short* __restrict__ vah,
    const short* __restrict__ vth, const float* __restrict__ gate,
    float* __restrict__ part)
{
  __shared__ float qs[HD][TT];
  __shared__ float sc[TT][176];
  __shared__ float msh[TT], lsh[TT];
  const int tid = threadIdx.x;
  const int bh = blockIdx.x;
  const int ch = blockIdx.y;
  const float scale = 0.09449111825230681f;  // 1/sqrt(112)
  const int nk = (ch == 0) ? (TT + KA) : ((ch == 3) ? 170 : 171);
  const int t0 = (ch >= 1) ? (ch - 1) * 171 : 0;

  for (int idx = tid; idx < TT * HD; idx += 256) {
    const int t = idx / HD, d = idx % HD;
    qs[d][t] = bf2f(qh[((size_t)bh * TT + t) * HD + d]);
  }
  __syncthreads();

  if (tid < nk) {
    const short* kp;
    float s = scale;
    if (ch == 0) {
      kp = (tid < TT) ? ksh + ((size_t)bh * TT + tid) * HD
                      : kah + ((size_t)bh * KA + (tid - TT)) * HD;
    } else {
      kp = kth + ((size_t)bh * KT + t0 + tid) * HD;
      s = scale * tanhf(gate[0]);
    }
    float dot[TT] = {};
    for (int d8 = 0; d8 < HD; d8 += 8) {
      const bf16x8_t kv8 = *(const bf16x8_t*)(kp + d8);
#pragma unroll
      for (int j = 0; j < 8; ++j) {
        const float kv = bf2f(kv8[j]);
#pragma unroll
        for (int t = 0; t < TT; ++t) dot[t] = fmaf(qs[d8 + j][t], kv, dot[t]);
      }
    }
#pragma unroll
    for (int t = 0; t < TT; ++t) sc[t][tid] = dot[t] * s;
  }
  __syncthreads();

  const int wave = tid >> 6, lane = tid & 63;
  for (int t = wave; t < TT; t += 4) {
    float m = -1e30f;
    for (int k = lane; k < nk; k += 64) m = fmaxf(m, sc[t][k]);
#pragma unroll
    for (int o = 32; o >= 1; o >>= 1) m = fmaxf(m, __shfl_xor(m, o));
    float sum = 0.f;
    for (int k = lane; k < nk; k += 64) {
      const float e = expf(sc[t][k] - m);
      sc[t][k] = e;
      sum += e;
    }
#pragma unroll
    for (int o = 32; o >= 1; o >>= 1) sum += __shfl_xor(sum, o);
    if (lane == 0) { msh[t] = m; lsh[t] = sum; }
  }
  __syncthreads();

  float* pb = part + (size_t)(bh * NCH + ch) * PSTRIDE;
  for (int idx = tid; idx < TT * HD; idx += 256) {
    const int t = idx / HD, d = idx % HD;
    float acc = 0.f;
    if (ch == 0) {
      const short* vs = vsh + (size_t)bh * TT * HD + d;
#pragma unroll
      for (int k = 0; k < TT; ++k)
        acc = fmaf(sc[t][k], bf2f(vs[(size_t)k * HD]), acc);
      const short* va = vah + (size_t)bh * KA * HD + d;
      for (int k = 0; k < KA; ++k)
        acc = fmaf(sc[t][TT + k], bf2f(va[(size_t)k * HD]), acc);
    } else {
      const short* vt = vth + ((size_t)bh * KT + t0) * HD + d;
      for (int k = 0; k < nk; ++k)
        acc = fmaf(sc[t][k], bf2f(vt[(size_t)k * HD]), acc);
    }
    pb[t * HD + d] = acc;
  }
  if (tid < TT) {
    pb[TT * HD + tid] = msh[tid];
    pb[TT * HD + TT + tid] = lsh[tid];
  }
}

__global__ __launch_bounds__(256) void attn_reduce(
    const float* __restrict__ part, short* __restrict__ out)
{
  __shared__ float fac[NCH][TT], inv[TT];
  const int tid = threadIdx.x;
  const int bh = blockIdx.x, b = bh >> 3, h = bh & 7;
  const float* pb = part + (size_t)bh * NCH * PSTRIDE;
  if (tid < TT) {
    const int t = tid;
    float M = -1e30f;
#pragma unroll
    for (int c = 0; c < NCH; ++c) M = fmaxf(M, pb[c * PSTRIDE + TT * HD + t]);
    float S = 0.f;
#pragma unroll
    for (int c = 0; c < NCH; ++c) {
      const float f = expf(pb[c * PSTRIDE + TT * HD + t] - M);
      fac[c][t] = f;
      S += pb[c * PSTRIDE + TT * HD + TT + t] * f;
    }
    inv[t] = 1.f / S;
  }
  __syncthreads();
  for (int idx = tid; idx < TT * HD; idx += 256) {
    const int t = idx / HD, d = idx % HD;
    float o = 0.f;
#pragma unroll
    for (int c = 0; c < NCH; ++c) o = fmaf(pb[c * PSTRIDE + t * HD + d], fac[c][t], o);
    out[(size_t)(b * TT + t) * DIM + h * HD + d] = f2bf(o * inv[t]);
  }
}

// ================= layernorm: fp32 in -> bf16 out =================
__global__ __launch_bounds__(256) void ln_kernel(
    const float* __restrict__ y, const float* __restrict__ g,
    const float* __restrict__ beta, short* __restrict__ yn)
{
  __shared__ float s1[4], s2[4];
  const int r = blockIdx.x, tid = threadIdx.x;
  const float* row = y + (size_t)r * DIM;
  float sum = 0.f, sq = 0.f;
  for (int c = tid; c < DIM; c += 256) {
    const float v = row[c];
    sum += v;
    sq = fmaf(v, v, sq);
  }
#pragma unroll
  for (int o = 32; o >= 1; o >>= 1) {
    sum += __shfl_xor(sum, o);
    sq  += __shfl_xor(sq, o);
  }
  const int wave = tid >> 6, lane = tid & 63;
  if (lane == 0) { s1[wave] = sum; s2[wave] = sq; }
  __syncthreads();
  sum = s1[0] + s1[1] + s1[2] + s1[3];
  sq  = s2[0] + s2[1] + s2[2] + s2[3];
  const float mu = sum / DIM;
  const float var = sq / DIM - mu * mu;
  const float rstd = 1.f / sqrtf(var + 1e-5f);
  for (int c = tid; c < DIM; c += 256)
    yn[(size_t)r * DIM + c] = f2bf((row[c] - mu) * rstd * g[c] + beta[c]);
}

// ================= launch =================
extern "C" void kernel_launch(void* const* d_in, const int* in_sizes, int n_in,
                              void* d_out, int out_size, void* d_ws, size_t ws_size,
                              hipStream_t stream)
{
  const float* x   = (const float*)d_in[0];
  const float* h_a = (const float*)d_in[1];
  const float* h_t = (const float*)d_in[2];
  const float* p   = (const float*)d_in[3];
  const float* Wq  = (const float*)d_in[4];  const float* bq  = (const float*)d_in[5];
  const float* Wks = (const float*)d_in[6];  const float* bks = (const float*)d_in[7];
  const float* Wvs = (const float*)d_in[8];  const float* bvs = (const float*)d_in[9];
  const float* Wka = (const float*)d_in[10]; const float* bka = (const float*)d_in[11];
  const float* Wva = (const float*)d_in[12]; const float* bva = (const float*)d_in[13];
  const float* Wkt = (const float*)d_in[14]; const float* bkt = (const float*)d_in[15];
  const float* Wvt = (const float*)d_in[16]; const float* bvt = (const float*)d_in[17];
  const float* Wo  = (const float*)d_in[18]; const float* bo  = (const float*)d_in[19];
  const float* Wf  = (const float*)d_in[20]; const float* bf_ = (const float*)d_in[21];
  const float* gate = (const float*)d_in[22];
  const float* ln_g = (const float*)d_in[23];
  const float* ln_b = (const float*)d_in[24];

  // ---- workspace (bytes); total 161.7 MB < proven 167.7 MB ----
  const size_t SZ_HAD  = (size_t)KAPAD * DIM * 2;        // 7,569,408 (row-major padded)
  const size_t SZ_SM   = (size_t)BB * TT * DIM * 2;      //   917,504
  const size_t SZ_AHM  = (size_t)BB * NH * KA * HD * 2;  // 7,454,720 head-major
  const size_t SZ_THM  = (size_t)BB * NH * KT * HD * 2;  // 58,720,256 head-major
  const size_t SZ_WT   = (size_t)9 * DD * 2;             // 14,450,688
  const size_t needed = SZ_HAD + SZ_SM * 4 + SZ_AHM * 2 + SZ_THM * 2 + SZ_WT
                        + SZ_SM + (size_t)BB * TT * DIM * 4 + SZ_SM;
  if (ws_size < needed) return;

  char* wsp = (char*)d_ws;
  short* hadb = (short*)wsp; wsp += SZ_HAD;
  short* xb   = (short*)wsp; wsp += SZ_SM;
  short* qh   = (short*)wsp; wsp += SZ_SM;
  short* ksh  = (short*)wsp; wsp += SZ_SM;
  short* vsh  = (short*)wsp; wsp += SZ_SM;
  short* kah  = (short*)wsp; wsp += SZ_AHM;
  short* vah  = (short*)wsp; wsp += SZ_AHM;
  short* kth  = (short*)wsp; wsp += SZ_THM;
  short* vth  = (short*)wsp; wsp += SZ_THM;
  short* WtA  = (short*)wsp; wsp += SZ_WT;
  short* attn_outb = (short*)wsp; wsp += SZ_SM;
  float* yb   = (float*)wsp; wsp += (size_t)BB * TT * DIM * 4;
  short* ynb  = (short*)wsp; wsp += SZ_SM;
  float* part = (float*)hadb;   // 7.47 MB aliases hadb (dead after A-group GEMM)

  dim3 blk(256);

  // 0) prep
  W9 w9; const float* Ws[9] = {Wq, Wks, Wvs, Wka, Wva, Wkt, Wvt, Wo, Wf};
  for (int i = 0; i < 9; ++i) w9.w[i] = Ws[i];
  prep<<<9128, blk, 0, stream>>>(w9, WtA, x, xb, h_a, p, hadb);

  // 1) mega-GEMM: T (fp32 A, XCD-swizzled, 3584) + A-group (462) + S-group (84)
  GemmJob JT = {}, JA = {}, JS = {};
  JT.A = h_t; JT.Wt = WtA + (size_t)5 * DD; JT.nx = 14; JT.base = 0;
  JT.aF = 1; JT.xsw = 1; JT.rowsb = 256;
  JT.bias[0] = bkt; JT.outB[0] = kth; JT.epi[0] = EPI_ROPE; JT.pos_mod[0] = KT; JT.okind[0] = OUT_T;
  JT.bias[1] = bvt; JT.outB[1] = vth; JT.epi[1] = EPI_NONE; JT.pos_mod[1] = 1;  JT.okind[1] = OUT_T;
  JA.A = hadb; JA.Wt = WtA + (size_t)3 * DD; JA.nx = 14; JA.base = 3584;
  JA.aF = 0; JA.xsw = 0; JA.rowsb = 33;
  JA.bias[0] = bka; JA.outB[0] = kah; JA.epi[0] = EPI_ROPE; JA.pos_mod[0] = KA; JA.okind[0] = OUT_A;
  JA.bias[1] = bva; JA.outB[1] = vah; JA.epi[1] = EPI_NONE; JA.pos_mod[1] = 1;  JA.okind[1] = OUT_A;
  JS.A = xb; JS.Wt = WtA; JS.nx = 21; JS.base = 3584 + 462;
  JS.aF = 0; JS.xsw = 0; JS.rowsb = 4;
  JS.bias[0] = bq;  JS.outB[0] = qh;  JS.epi[0] = EPI_ROPE; JS.pos_mod[0] = TT; JS.okind[0] = OUT_S;
  JS.bias[1] = bks; JS.outB[1] = ksh; JS.epi[1] = EPI_ROPE; JS.pos_mod[1] = TT; JS.okind[1] = OUT_S;
  JS.bias[2] = bvs; JS.outB[2] = vsh; JS.epi[2] = EPI_NONE; JS.pos_mod[2] = 1;  JS.okind[2] = OUT_S;
  gemm_multi<<<3584 + 462 + 84, blk, 0, stream>>>(JT, JA, JS);

  // 2) attention: split-K partials + combine
  attn_part<<<dim3(BB * NH, NCH), blk, 0, stream>>>(qh, ksh, kah, kth, vsh, vah, vth,
                                                    gate, part);
  attn_reduce<<<BB * NH, blk, 0, stream>>>(part, attn_outb);

  // 3) out-proj + residual, LN, FFN + ReLU
  {
    GemmJob J = {};
    J.A = attn_outb; J.Wt = WtA + (size_t)7 * DD; J.nx = 7; J.base = 0;
    J.aF = 0; J.xsw = 0; J.rowsb = 4;
    J.bias[0] = bo; J.outF[0] = yb; J.epi[0] = EPI_RESID; J.pos_mod[0] = 1; J.okind[0] = OUT_F32;
    J.resid = x;
    gemm_single<<<28, blk, 0, stream>>>(J);
  }
  ln_kernel<<<BB * TT, blk, 0, stream>>>(yb, ln_g, ln_b, ynb);
  {
    GemmJob J = {};
    J.A = ynb; J.Wt = WtA + (size_t)8 * DD; J.nx = 7; J.base = 0;
    J.aF = 0; J.xsw = 0; J.rowsb = 4;
    J.bias[0] = bf_; J.outF[0] = (float*)d_out; J.epi[0] = EPI_RELU; J.pos_mod[0] = 1; J.okind[0] = OUT_F32;
    gemm_single<<<28, blk, 0, stream>>>(J);
  }
}